// Round 1
// baseline (365.285 us; speedup 1.0000x reference)
//
#include <hip/hip_runtime.h>

// ---------------------------------------------------------------------------
// GCN 3-layer forward on MI355X.
//   norm fusion: hs = (h@W) * dis[row]  (GEMM epilogue)
//   out[n] = relu( dis[n] * (sum_{s in in(n)} hs[s] + hs[n]) + b )
// CSR built on-device each call (ws is re-poisoned before every timed call).
// ---------------------------------------------------------------------------

// ---- edge-index dtype detection (int32 vs int64 device buffer) -------------
__global__ void detect_i64_kernel(const int* __restrict__ q, int count32, int* flag) {
    if (blockIdx.x == 0 && threadIdx.x == 0) {
        int z = 1;
        int lim = count32 < 128 ? count32 : 128;
        for (int i = 1; i < lim; i += 2) {
            if (q[i] != 0) { z = 0; break; }
        }
        *flag = z;  // 1 => buffer holds int64 little-endian values
    }
}

__device__ __forceinline__ int edge_at(const void* p, long long i, int is64) {
    if (is64) return (int)((const long long*)p)[i];
    return ((const int*)p)[i];
}

// ---- degree / dis ----------------------------------------------------------
__global__ void init_deg_kernel(int* __restrict__ deg, int N) {
    int i = blockIdx.x * blockDim.x + threadIdx.x;
    if (i < N) deg[i] = 1;  // self-loop
}

__global__ void count_deg_kernel(const void* __restrict__ ei, const int* __restrict__ flag,
                                 int* __restrict__ deg, int E) {
    int e = blockIdx.x * blockDim.x + threadIdx.x;
    if (e < E) {
        int d = edge_at(ei, (long long)E + e, *flag);
        atomicAdd(&deg[d], 1);
    }
}

__global__ void dis_kernel(const int* __restrict__ deg, float* __restrict__ dis, int N) {
    int i = blockIdx.x * blockDim.x + threadIdx.x;
    if (i < N) dis[i] = rsqrtf((float)deg[i]);
}

// ---- exclusive scan of (deg-1) over N<=20480 elements, single block --------
#define SCAN_THREADS 1024
#define SCAN_CHUNK 20
__global__ __launch_bounds__(SCAN_THREADS) void scan_kernel(
        const int* __restrict__ deg, int* __restrict__ off, int N, int E) {
    __shared__ int sums[SCAN_THREADS];
    int t = threadIdx.x;
    int base = t * SCAN_CHUNK;
    int local[SCAN_CHUNK];
    int s = 0;
    for (int i = 0; i < SCAN_CHUNK; ++i) {
        int idx = base + i;
        int v = (idx < N) ? (deg[idx] - 1) : 0;
        local[i] = s;
        s += v;
    }
    sums[t] = s;
    __syncthreads();
    // Hillis-Steele inclusive scan over 1024 partial sums
    for (int d = 1; d < SCAN_THREADS; d <<= 1) {
        int v = (t >= d) ? sums[t - d] : 0;
        __syncthreads();
        sums[t] += v;
        __syncthreads();
    }
    int prefix = (t > 0) ? sums[t - 1] : 0;
    for (int i = 0; i < SCAN_CHUNK; ++i) {
        int idx = base + i;
        if (idx < N) off[idx] = prefix + local[i];
    }
    if (t == 0) off[N] = E;
}

__global__ void cursor_kernel(const int* __restrict__ off, int* __restrict__ cur, int N) {
    int i = blockIdx.x * blockDim.x + threadIdx.x;
    if (i < N) cur[i] = off[i];
}

__global__ void fill_kernel(const void* __restrict__ ei, const int* __restrict__ flag,
                            int* __restrict__ cur, int* __restrict__ csr, int E) {
    int e = blockIdx.x * blockDim.x + threadIdx.x;
    if (e < E) {
        int is64 = *flag;
        int s = edge_at(ei, e, is64);
        int d = edge_at(ei, (long long)E + e, is64);
        int slot = atomicAdd(&cur[d], 1);
        csr[slot] = s;
    }
}

// ---- fp32 tiled GEMM, epilogue scales row by dis[row] ----------------------
// C[M,N] = (A[M,K] @ W[K,N]) * dis[row]
#define BM 64
#define BN 64
#define BK 16
__global__ __launch_bounds__(256) void gemm_scaled_kernel(
        const float* __restrict__ A, const float* __restrict__ W,
        const float* __restrict__ dis, float* __restrict__ C,
        int M, int N, int K) {
    __shared__ float As[BK][BM + 1];
    __shared__ float Ws[BK][BN];
    int tid = threadIdx.x;
    int tx = tid & 15, ty = tid >> 4;
    int row0 = blockIdx.x * BM, col0 = blockIdx.y * BN;
    float acc[4][4] = {};
    for (int k0 = 0; k0 < K; k0 += BK) {
        // A tile: 64 rows x 16 cols
        #pragma unroll
        for (int t = 0; t < 4; ++t) {
            int i = tid + t * 256;
            int r = i >> 4, c = i & 15;
            int gr = row0 + r;
            As[c][r] = (gr < M) ? A[(long long)gr * K + k0 + c] : 0.f;
        }
        // W tile: 16 rows x 64 cols
        #pragma unroll
        for (int t = 0; t < 4; ++t) {
            int i = tid + t * 256;
            int r = i >> 6, c = i & 63;
            Ws[r][c] = W[(long long)(k0 + r) * N + col0 + c];
        }
        __syncthreads();
        #pragma unroll
        for (int kk = 0; kk < BK; ++kk) {
            float a[4], b[4];
            #pragma unroll
            for (int j = 0; j < 4; ++j) a[j] = As[kk][ty * 4 + j];
            #pragma unroll
            for (int j = 0; j < 4; ++j) b[j] = Ws[kk][tx * 4 + j];
            #pragma unroll
            for (int i = 0; i < 4; ++i)
                #pragma unroll
                for (int j = 0; j < 4; ++j)
                    acc[i][j] = fmaf(a[i], b[j], acc[i][j]);
        }
        __syncthreads();
    }
    #pragma unroll
    for (int i = 0; i < 4; ++i) {
        int r = row0 + ty * 4 + i;
        if (r >= M) continue;
        float s = dis[r];
        #pragma unroll
        for (int j = 0; j < 4; ++j) {
            C[(long long)r * N + col0 + tx * 4 + j] = acc[i][j] * s;
        }
    }
}

// ---- aggregation: one block per node, one thread per feature ---------------
__global__ void agg_kernel(const float* __restrict__ hs, const float* __restrict__ dis,
                           const float* __restrict__ bias, const int* __restrict__ off,
                           const int* __restrict__ csr, float* __restrict__ out,
                           int F, int do_relu) {
    int n = blockIdx.x;
    int f = threadIdx.x;                  // blockDim.x == F
    float acc = hs[(long long)n * F + f]; // self-loop (already dis[n]-scaled)
    int s0 = off[n], s1 = off[n + 1];
    for (int j = s0; j < s1; ++j) {
        int s = csr[j];
        acc += hs[(long long)s * F + f];
    }
    float v = dis[n] * acc + bias[f];
    if (do_relu) v = fmaxf(v, 0.f);
    out[(long long)n * F + f] = v;
}

// ---------------------------------------------------------------------------
extern "C" void kernel_launch(void* const* d_in, const int* in_sizes, int n_in,
                              void* d_out, int out_size, void* d_ws, size_t ws_size,
                              hipStream_t stream) {
    const float* x  = (const float*)d_in[0];
    const float* W1 = (const float*)d_in[1];
    const float* b1 = (const float*)d_in[2];
    const float* W2 = (const float*)d_in[3];
    const float* b2 = (const float*)d_in[4];
    const float* W3 = (const float*)d_in[5];
    const float* b3 = (const float*)d_in[6];
    const void*  ei = d_in[7];

    const int N = in_sizes[0] / 256;      // 20000
    const int E = in_sizes[7] / 2;        // 320000

    // workspace carve-out (256B aligned)
    size_t cur = 0;
    auto alloc = [&](size_t bytes) -> void* {
        void* p = (char*)d_ws + cur;
        cur += (bytes + 255) & ~(size_t)255;
        return p;
    };
    int*   flag   = (int*)alloc(4);
    int*   deg    = (int*)alloc((size_t)N * 4);
    float* dis    = (float*)alloc((size_t)N * 4);
    int*   off    = (int*)alloc((size_t)(N + 1) * 4);
    int*   curs   = (int*)alloc((size_t)N * 4);
    int*   csr    = (int*)alloc((size_t)E * 4);
    float* bufA   = (float*)alloc((size_t)N * 256 * 4);
    float* bufB   = (float*)alloc((size_t)N * 256 * 4);
    (void)ws_size; (void)n_in; (void)out_size;

    const int T = 256;
    int gN = (N + T - 1) / T;
    int gE = (E + T - 1) / T;

    // --- normalization + CSR build ---
    detect_i64_kernel<<<1, 64, 0, stream>>>((const int*)ei, in_sizes[7] * 2, flag);
    init_deg_kernel<<<gN, T, 0, stream>>>(deg, N);
    count_deg_kernel<<<gE, T, 0, stream>>>(ei, flag, deg, E);
    dis_kernel<<<gN, T, 0, stream>>>(deg, dis, N);
    scan_kernel<<<1, SCAN_THREADS, 0, stream>>>(deg, off, N, E);
    cursor_kernel<<<gN, T, 0, stream>>>(off, curs, N);
    fill_kernel<<<gE, T, 0, stream>>>(ei, flag, curs, csr, E);

    // --- layer 1: x[20000,256] @ W1[256,256] -> bufA; agg -> bufB ---
    {
        dim3 grid((N + BM - 1) / BM, 256 / BN);
        gemm_scaled_kernel<<<grid, 256, 0, stream>>>(x, W1, dis, bufA, N, 256, 256);
        agg_kernel<<<N, 256, 0, stream>>>(bufA, dis, b1, off, csr, bufB, 256, 1);
    }
    // --- layer 2: bufB[20000,256] @ W2[256,128] -> bufA; agg -> bufB ---
    {
        dim3 grid((N + BM - 1) / BM, 128 / BN);
        gemm_scaled_kernel<<<grid, 256, 0, stream>>>(bufB, W2, dis, bufA, N, 128, 256);
        agg_kernel<<<N, 128, 0, stream>>>(bufA, dis, b2, off, csr, bufB, 128, 1);
    }
    // --- layer 3: bufB[20000,128] @ W3[128,64] -> bufA; agg -> d_out ---
    {
        dim3 grid((N + BM - 1) / BM, 64 / BN);
        gemm_scaled_kernel<<<grid, 256, 0, stream>>>(bufB, W3, dis, bufA, N, 64, 128);
        agg_kernel<<<N, 64, 0, stream>>>(bufA, dis, b3, off, csr, (float*)d_out, 64, 0);
    }
}

// Round 2
// 313.920 us; speedup vs baseline: 1.1636x; 1.1636x over previous
//
#include <hip/hip_runtime.h>

// ---------------------------------------------------------------------------
// GCN 3-layer forward on MI355X.
//   norm fusion: hs = (h@W) * dis[row]  (GEMM epilogue)
//   out[n] = relu( dis[n] * (sum_{s in in(n)} hs[s] + hs[n]) + b )
// R2: wave-per-node float4 aggregation (MLP), 128x64 GEMM w/ ds_read_b128.
// ---------------------------------------------------------------------------

// ---- edge-index dtype detection (int32 vs int64 device buffer) -------------
__global__ void detect_i64_kernel(const int* __restrict__ q, int count32, int* flag) {
    if (blockIdx.x == 0 && threadIdx.x == 0) {
        int z = 1;
        int lim = count32 < 128 ? count32 : 128;
        for (int i = 1; i < lim; i += 2) {
            if (q[i] != 0) { z = 0; break; }
        }
        *flag = z;  // 1 => buffer holds int64 little-endian values
    }
}

__device__ __forceinline__ int edge_at(const void* p, long long i, int is64) {
    if (is64) return (int)((const long long*)p)[i];
    return ((const int*)p)[i];
}

// ---- degree / dis ----------------------------------------------------------
__global__ void init_deg_kernel(int* __restrict__ deg, int N) {
    int i = blockIdx.x * blockDim.x + threadIdx.x;
    if (i < N) deg[i] = 1;  // self-loop
}

__global__ void count_deg_kernel(const void* __restrict__ ei, const int* __restrict__ flag,
                                 int* __restrict__ deg, int E) {
    int e = blockIdx.x * blockDim.x + threadIdx.x;
    if (e < E) {
        int d = edge_at(ei, (long long)E + e, *flag);
        atomicAdd(&deg[d], 1);
    }
}

__global__ void dis_kernel(const int* __restrict__ deg, float* __restrict__ dis, int N) {
    int i = blockIdx.x * blockDim.x + threadIdx.x;
    if (i < N) dis[i] = rsqrtf((float)deg[i]);
}

// ---- exclusive scan of (deg-1) over N<=20480 elements, single block --------
#define SCAN_THREADS 1024
#define SCAN_CHUNK 20
__global__ __launch_bounds__(SCAN_THREADS) void scan_kernel(
        const int* __restrict__ deg, int* __restrict__ off, int N, int E) {
    __shared__ int sums[SCAN_THREADS];
    int t = threadIdx.x;
    int base = t * SCAN_CHUNK;
    int local[SCAN_CHUNK];
    int s = 0;
    for (int i = 0; i < SCAN_CHUNK; ++i) {
        int idx = base + i;
        int v = (idx < N) ? (deg[idx] - 1) : 0;
        local[i] = s;
        s += v;
    }
    sums[t] = s;
    __syncthreads();
    for (int d = 1; d < SCAN_THREADS; d <<= 1) {
        int v = (t >= d) ? sums[t - d] : 0;
        __syncthreads();
        sums[t] += v;
        __syncthreads();
    }
    int prefix = (t > 0) ? sums[t - 1] : 0;
    for (int i = 0; i < SCAN_CHUNK; ++i) {
        int idx = base + i;
        if (idx < N) off[idx] = prefix + local[i];
    }
    if (t == 0) off[N] = E;
}

__global__ void cursor_kernel(const int* __restrict__ off, int* __restrict__ cur, int N) {
    int i = blockIdx.x * blockDim.x + threadIdx.x;
    if (i < N) cur[i] = off[i];
}

__global__ void fill_kernel(const void* __restrict__ ei, const int* __restrict__ flag,
                            int* __restrict__ cur, int* __restrict__ csr, int E) {
    int e = blockIdx.x * blockDim.x + threadIdx.x;
    if (e < E) {
        int is64 = *flag;
        int s = edge_at(ei, e, is64);
        int d = edge_at(ei, (long long)E + e, is64);
        int slot = atomicAdd(&cur[d], 1);
        csr[slot] = s;
    }
}

// ---- fp32 tiled GEMM, epilogue scales row by dis[row] ----------------------
// C[M,N] = (A[M,K] @ W[K,N]) * dis[row]
// BM=128, BN=64, BK=16; 256 threads; 8x4 per-thread tile; float4 LDS reads.
#define BM 128
#define BN 64
#define BK 16
__global__ __launch_bounds__(256) void gemm_scaled_kernel(
        const float* __restrict__ A, const float* __restrict__ W,
        const float* __restrict__ dis, float* __restrict__ C,
        int M, int N, int K) {
    __shared__ __align__(16) float As[BK][BM + 4];  // stride 132 fl = 528B (16B-aligned)
    __shared__ __align__(16) float Ws[BK][BN + 4];  // stride 68 fl = 272B (16B-aligned)
    int tid = threadIdx.x;
    int tx = tid & 15;        // col group: 16 x 4 cols
    int ty = tid >> 4;        // row group: 16 x 8 rows
    int row0 = blockIdx.x * BM, col0 = blockIdx.y * BN;
    float acc[8][4] = {};
    for (int k0 = 0; k0 < K; k0 += BK) {
        // A tile: 128 rows x 16 cols, transposed into As[c][r]
        #pragma unroll
        for (int p = 0; p < 2; ++p) {
            int i = tid + p * 256;
            int r = i >> 2;
            int c = (i & 3) * 4;
            int gr = row0 + r;
            float4 v = make_float4(0.f, 0.f, 0.f, 0.f);
            if (gr < M) v = *(const float4*)&A[(long long)gr * K + k0 + c];
            As[c + 0][r] = v.x; As[c + 1][r] = v.y;
            As[c + 2][r] = v.z; As[c + 3][r] = v.w;
        }
        // W tile: 16 rows x 64 cols
        {
            int r = tid >> 4, c = (tid & 15) * 4;
            *(float4*)&Ws[r][c] = *(const float4*)&W[(long long)(k0 + r) * N + col0 + c];
        }
        __syncthreads();
        #pragma unroll
        for (int kk = 0; kk < BK; ++kk) {
            float4 a0 = *(const float4*)&As[kk][ty * 8];
            float4 a1 = *(const float4*)&As[kk][ty * 8 + 4];
            float4 b4 = *(const float4*)&Ws[kk][tx * 4];
            float a[8] = {a0.x, a0.y, a0.z, a0.w, a1.x, a1.y, a1.z, a1.w};
            float b[4] = {b4.x, b4.y, b4.z, b4.w};
            #pragma unroll
            for (int i = 0; i < 8; ++i)
                #pragma unroll
                for (int j = 0; j < 4; ++j)
                    acc[i][j] = fmaf(a[i], b[j], acc[i][j]);
        }
        __syncthreads();
    }
    #pragma unroll
    for (int i = 0; i < 8; ++i) {
        int r = row0 + ty * 8 + i;
        if (r >= M) continue;
        float s = dis[r];
        float4 o = make_float4(acc[i][0] * s, acc[i][1] * s, acc[i][2] * s, acc[i][3] * s);
        *(float4*)&C[(long long)r * N + col0 + tx * 4] = o;
    }
}

// ---- aggregation: one WAVE per node, lane holds VEC=F/64 feats -------------
template <int VEC>
__device__ __forceinline__ void vload(float* dst, const float* src) {
    if constexpr (VEC == 4) {
        float4 v = *(const float4*)src;
        dst[0] = v.x; dst[1] = v.y; dst[2] = v.z; dst[3] = v.w;
    } else if constexpr (VEC == 2) {
        float2 v = *(const float2*)src;
        dst[0] = v.x; dst[1] = v.y;
    } else {
        dst[0] = *src;
    }
}

template <int F>
__global__ __launch_bounds__(256) void agg_kernel(
        const float* __restrict__ hs, const float* __restrict__ dis,
        const float* __restrict__ bias, const int* __restrict__ off,
        const int* __restrict__ csr, float* __restrict__ out,
        int N, int do_relu) {
    constexpr int VEC = F / 64;
    int wave = threadIdx.x >> 6;
    int lane = threadIdx.x & 63;
    int n = blockIdx.x * 4 + wave;
    if (n >= N) return;
    int fo = lane * VEC;
    float acc[VEC];
    vload<VEC>(acc, hs + (long long)n * F + fo);  // self-loop term
    int s0 = off[n], s1 = off[n + 1];
    int j = s0;
    // 4-way unrolled gather: 4 independent vector loads in flight per lane
    for (; j + 4 <= s1; j += 4) {
        int i0 = csr[j], i1 = csr[j + 1], i2 = csr[j + 2], i3 = csr[j + 3];
        float v0[VEC], v1[VEC], v2[VEC], v3[VEC];
        vload<VEC>(v0, hs + (long long)i0 * F + fo);
        vload<VEC>(v1, hs + (long long)i1 * F + fo);
        vload<VEC>(v2, hs + (long long)i2 * F + fo);
        vload<VEC>(v3, hs + (long long)i3 * F + fo);
        #pragma unroll
        for (int v = 0; v < VEC; ++v)
            acc[v] += (v0[v] + v1[v]) + (v2[v] + v3[v]);
    }
    for (; j < s1; ++j) {
        float v0[VEC];
        vload<VEC>(v0, hs + (long long)csr[j] * F + fo);
        #pragma unroll
        for (int v = 0; v < VEC; ++v) acc[v] += v0[v];
    }
    float d = dis[n];
    float bv[VEC];
    vload<VEC>(bv, bias + fo);
    float o[VEC];
    #pragma unroll
    for (int v = 0; v < VEC; ++v) {
        float val = d * acc[v] + bv[v];
        o[v] = do_relu ? fmaxf(val, 0.f) : val;
    }
    float* op = out + (long long)n * F + fo;
    if constexpr (VEC == 4)      *(float4*)op = make_float4(o[0], o[1], o[2], o[3]);
    else if constexpr (VEC == 2) *(float2*)op = make_float2(o[0], o[1]);
    else                         *op = o[0];
}

// ---------------------------------------------------------------------------
extern "C" void kernel_launch(void* const* d_in, const int* in_sizes, int n_in,
                              void* d_out, int out_size, void* d_ws, size_t ws_size,
                              hipStream_t stream) {
    const float* x  = (const float*)d_in[0];
    const float* W1 = (const float*)d_in[1];
    const float* b1 = (const float*)d_in[2];
    const float* W2 = (const float*)d_in[3];
    const float* b2 = (const float*)d_in[4];
    const float* W3 = (const float*)d_in[5];
    const float* b3 = (const float*)d_in[6];
    const void*  ei = d_in[7];

    const int N = in_sizes[0] / 256;      // 20000
    const int E = in_sizes[7] / 2;        // 320000

    size_t cur = 0;
    auto alloc = [&](size_t bytes) -> void* {
        void* p = (char*)d_ws + cur;
        cur += (bytes + 255) & ~(size_t)255;
        return p;
    };
    int*   flag   = (int*)alloc(4);
    int*   deg    = (int*)alloc((size_t)N * 4);
    float* dis    = (float*)alloc((size_t)N * 4);
    int*   off    = (int*)alloc((size_t)(N + 1) * 4);
    int*   curs   = (int*)alloc((size_t)N * 4);
    int*   csr    = (int*)alloc((size_t)E * 4);
    float* bufA   = (float*)alloc((size_t)N * 256 * 4);
    float* bufB   = (float*)alloc((size_t)N * 256 * 4);
    (void)ws_size; (void)n_in; (void)out_size;

    const int T = 256;
    int gN = (N + T - 1) / T;
    int gE = (E + T - 1) / T;
    int gAgg = (N + 3) / 4;   // 4 waves (nodes) per 256-thread block

    // --- normalization + CSR build ---
    detect_i64_kernel<<<1, 64, 0, stream>>>((const int*)ei, in_sizes[7] * 2, flag);
    init_deg_kernel<<<gN, T, 0, stream>>>(deg, N);
    count_deg_kernel<<<gE, T, 0, stream>>>(ei, flag, deg, E);
    dis_kernel<<<gN, T, 0, stream>>>(deg, dis, N);
    scan_kernel<<<1, SCAN_THREADS, 0, stream>>>(deg, off, N, E);
    cursor_kernel<<<gN, T, 0, stream>>>(off, curs, N);
    fill_kernel<<<gE, T, 0, stream>>>(ei, flag, curs, csr, E);

    // --- layer 1: x[N,256] @ W1[256,256] -> bufA; agg -> bufB ---
    {
        dim3 grid((N + BM - 1) / BM, 256 / BN);
        gemm_scaled_kernel<<<grid, 256, 0, stream>>>(x, W1, dis, bufA, N, 256, 256);
        agg_kernel<256><<<gAgg, 256, 0, stream>>>(bufA, dis, b1, off, csr, bufB, N, 1);
    }
    // --- layer 2: bufB[N,256] @ W2[256,128] -> bufA; agg -> bufB ---
    {
        dim3 grid((N + BM - 1) / BM, 128 / BN);
        gemm_scaled_kernel<<<grid, 256, 0, stream>>>(bufB, W2, dis, bufA, N, 128, 256);
        agg_kernel<128><<<gAgg, 256, 0, stream>>>(bufA, dis, b2, off, csr, bufB, N, 1);
    }
    // --- layer 3: bufB[N,128] @ W3[128,64] -> bufA; agg -> d_out ---
    {
        dim3 grid((N + BM - 1) / BM, 64 / BN);
        gemm_scaled_kernel<<<grid, 256, 0, stream>>>(bufB, W3, dis, bufA, N, 64, 128);
        agg_kernel<64><<<gAgg, 256, 0, stream>>>(bufA, dis, b3, off, csr, (float*)d_out, N, 0);
    }
}

// Round 3
// 236.218 us; speedup vs baseline: 1.5464x; 1.3289x over previous
//
#include <hip/hip_runtime.h>

// ---------------------------------------------------------------------------
// GCN 3-layer forward on MI355X — fp16 MFMA edition.
//   hs = (h@W) * dis[row]      (MFMA GEMM, fp16 in, fp32 acc, fp16 out)
//   out[n] = relu( dis[n] * (sum_in(n) hs[s] + hs[n]) + b )
//   W pre-transposed+converted to Wt[N][K] fp16 so both MFMA operands read
//   contiguous 16B fragments from LDS.
// ---------------------------------------------------------------------------

typedef _Float16 half8_t __attribute__((ext_vector_type(8)));
typedef _Float16 half4_t __attribute__((ext_vector_type(4)));
typedef _Float16 half2_t __attribute__((ext_vector_type(2)));
typedef float floatx16 __attribute__((ext_vector_type(16)));

// ---- edge-index dtype detection (int32 vs int64 device buffer) -------------
__global__ void detect_i64_kernel(const int* __restrict__ q, int count32, int* flag) {
    if (blockIdx.x == 0 && threadIdx.x == 0) {
        int z = 1;
        int lim = count32 < 128 ? count32 : 128;
        for (int i = 1; i < lim; i += 2) {
            if (q[i] != 0) { z = 0; break; }
        }
        *flag = z;  // 1 => buffer holds int64 little-endian values
    }
}

__device__ __forceinline__ int edge_at(const void* p, long long i, int is64) {
    if (is64) return (int)((const long long*)p)[i];
    return ((const int*)p)[i];
}

// ---- degree / dis ----------------------------------------------------------
__global__ void init_deg_kernel(int* __restrict__ deg, int N) {
    int i = blockIdx.x * blockDim.x + threadIdx.x;
    if (i < N) deg[i] = 1;  // self-loop
}

__global__ void count_deg_kernel(const void* __restrict__ ei, const int* __restrict__ flag,
                                 int* __restrict__ deg, int E) {
    int e = blockIdx.x * blockDim.x + threadIdx.x;
    if (e < E) {
        int d = edge_at(ei, (long long)E + e, *flag);
        atomicAdd(&deg[d], 1);
    }
}

__global__ void dis_kernel(const int* __restrict__ deg, float* __restrict__ dis, int N) {
    int i = blockIdx.x * blockDim.x + threadIdx.x;
    if (i < N) dis[i] = rsqrtf((float)deg[i]);
}

// ---- exclusive scan of (deg-1); also writes cursor copy --------------------
#define SCAN_THREADS 1024
#define SCAN_CHUNK 20
__global__ __launch_bounds__(SCAN_THREADS) void scan_kernel(
        const int* __restrict__ deg, int* __restrict__ off, int* __restrict__ curs,
        int N, int E) {
    __shared__ int sums[SCAN_THREADS];
    int t = threadIdx.x;
    int base = t * SCAN_CHUNK;
    int local[SCAN_CHUNK];
    int s = 0;
    for (int i = 0; i < SCAN_CHUNK; ++i) {
        int idx = base + i;
        int v = (idx < N) ? (deg[idx] - 1) : 0;
        local[i] = s;
        s += v;
    }
    sums[t] = s;
    __syncthreads();
    for (int d = 1; d < SCAN_THREADS; d <<= 1) {
        int v = (t >= d) ? sums[t - d] : 0;
        __syncthreads();
        sums[t] += v;
        __syncthreads();
    }
    int prefix = (t > 0) ? sums[t - 1] : 0;
    for (int i = 0; i < SCAN_CHUNK; ++i) {
        int idx = base + i;
        if (idx < N) { int o = prefix + local[i]; off[idx] = o; curs[idx] = o; }
    }
    if (t == 0) off[N] = E;
}

__global__ void fill_kernel(const void* __restrict__ ei, const int* __restrict__ flag,
                            int* __restrict__ cur, int* __restrict__ csr, int E) {
    int e = blockIdx.x * blockDim.x + threadIdx.x;
    if (e < E) {
        int is64 = *flag;
        int s = edge_at(ei, e, is64);
        int d = edge_at(ei, (long long)E + e, is64);
        int slot = atomicAdd(&cur[d], 1);
        csr[slot] = s;
    }
}

// ---- x fp32 -> fp16 --------------------------------------------------------
__global__ void convert_x_kernel(const float* __restrict__ x, _Float16* __restrict__ xh,
                                 int total4) {
    int i = blockIdx.x * blockDim.x + threadIdx.x;
    if (i < total4) {
        float4 v = *(const float4*)(x + (long long)i * 4);
        half4_t h;
        h[0] = (_Float16)v.x; h[1] = (_Float16)v.y;
        h[2] = (_Float16)v.z; h[3] = (_Float16)v.w;
        *(half4_t*)(xh + (long long)i * 4) = h;
    }
}

// ---- W[K][N] fp32 -> Wt[N][K] fp16 for all three weights -------------------
__global__ void prep_weights_kernel(const float* __restrict__ W1, const float* __restrict__ W2,
                                    const float* __restrict__ W3, _Float16* __restrict__ Wt1,
                                    _Float16* __restrict__ Wt2, _Float16* __restrict__ Wt3) {
    int id = blockIdx.x * blockDim.x + threadIdx.x;
    if (id < 65536) {                       // W1: 256x256 -> Wt1[256][256]
        int n = id >> 8, k = id & 255;
        Wt1[n * 256 + k] = (_Float16)W1[k * 256 + n];
    } else if (id < 98304) {                // W2: 256x128 -> Wt2[128][256]
        int i = id - 65536;
        int n = i >> 8, k = i & 255;
        Wt2[n * 256 + k] = (_Float16)W2[k * 128 + n];
    } else if (id < 106496) {               // W3: 128x64 -> Wt3[64][128]
        int i = id - 98304;
        int n = i >> 7, k = i & 127;
        Wt3[n * 128 + k] = (_Float16)W3[k * 64 + n];
    }
}

// ---- MFMA GEMM: C[M,N] = (A[M,K] @ Wt^T) * dis[row], fp16 out --------------
// Block 128x64 (4 waves M-stacked, wave tile 32x64 = 2 x mfma_32x32x16_f16).
// BK=32 (2 k-steps/iter), register-prefetch of next tile during MFMA.
__global__ __launch_bounds__(256) void gemm_mfma_kernel(
        const _Float16* __restrict__ A, const _Float16* __restrict__ Wt,
        const float* __restrict__ dis, _Float16* __restrict__ C,
        int M, int N, int K) {
    constexpr int BM = 128, BN = 64, BK = 32, PAD = 8;  // stride 40 halfs: 4-way max conflict
    __shared__ _Float16 As[BM][BK + PAD];
    __shared__ _Float16 Bs[BN][BK + PAD];
    __shared__ float disS[BM];
    const int tid = threadIdx.x;
    const int wave = tid >> 6, lane = tid & 63;
    const int row0 = blockIdx.x * BM, col0 = blockIdx.y * BN;

    if (tid < BM) { int r = row0 + tid; disS[tid] = (r < M) ? dis[r] : 0.f; }

    // staging map: A = 128 rows x 4 chunks(16B) -> 2 per thread; B = 64 x 4 -> 1
    const int ar0 = tid >> 2, ar1 = ar0 + 64;
    const int ac  = (tid & 3) * 8;          // half offset within row
    const int br  = tid >> 2;
    const int bc  = (tid & 3) * 8;
    const long long arow0 = (long long)(row0 + ar0) * K;
    const long long arow1 = (long long)(row0 + ar1) * K;
    const long long brow  = (long long)(col0 + br) * K;
    const bool a0ok = (row0 + ar0) < M, a1ok = (row0 + ar1) < M;
    const float4 f4z = make_float4(0.f, 0.f, 0.f, 0.f);

    float4 pa0 = a0ok ? *(const float4*)(A + arow0 + ac) : f4z;
    float4 pa1 = a1ok ? *(const float4*)(A + arow1 + ac) : f4z;
    float4 pb  = *(const float4*)(Wt + brow + bc);
    *(float4*)&As[ar0][ac] = pa0;
    *(float4*)&As[ar1][ac] = pa1;
    *(float4*)&Bs[br][bc]  = pb;
    __syncthreads();

    floatx16 acc0, acc1;
    #pragma unroll
    for (int i = 0; i < 16; ++i) { acc0[i] = 0.f; acc1[i] = 0.f; }

    const _Float16* ap  = &As[wave * 32 + (lane & 31)][(lane >> 5) * 8];
    const _Float16* bp0 = &Bs[lane & 31][(lane >> 5) * 8];
    const _Float16* bp1 = &Bs[32 + (lane & 31)][(lane >> 5) * 8];

    const int niter = K / BK;
    for (int it = 0; it < niter; ++it) {
        const bool more = (it + 1) < niter;
        if (more) {
            int k0 = (it + 1) * BK;
            pa0 = a0ok ? *(const float4*)(A + arow0 + k0 + ac) : f4z;
            pa1 = a1ok ? *(const float4*)(A + arow1 + k0 + ac) : f4z;
            pb  = *(const float4*)(Wt + brow + k0 + bc);
        }
        half8_t a0  = *(const half8_t*)ap;
        half8_t a1  = *(const half8_t*)(ap + 16);
        half8_t b00 = *(const half8_t*)bp0;
        half8_t b01 = *(const half8_t*)(bp0 + 16);
        half8_t b10 = *(const half8_t*)bp1;
        half8_t b11 = *(const half8_t*)(bp1 + 16);
        acc0 = __builtin_amdgcn_mfma_f32_32x32x16_f16(a0, b00, acc0, 0, 0, 0);
        acc1 = __builtin_amdgcn_mfma_f32_32x32x16_f16(a0, b10, acc1, 0, 0, 0);
        acc0 = __builtin_amdgcn_mfma_f32_32x32x16_f16(a1, b01, acc0, 0, 0, 0);
        acc1 = __builtin_amdgcn_mfma_f32_32x32x16_f16(a1, b11, acc1, 0, 0, 0);
        if (more) {
            __syncthreads();
            *(float4*)&As[ar0][ac] = pa0;
            *(float4*)&As[ar1][ac] = pa1;
            *(float4*)&Bs[br][bc]  = pb;
            __syncthreads();
        }
    }

    // epilogue: C/D layout col=lane&31, row=(reg&3)+8*(reg>>2)+4*(lane>>5)
    const int colb = lane & 31, q = lane >> 5;
    #pragma unroll
    for (int r = 0; r < 16; ++r) {
        int rl = wave * 32 + (r & 3) + 8 * (r >> 2) + 4 * q;
        int row = row0 + rl;
        if (row >= M) continue;
        float d = disS[rl];
        C[(long long)row * N + col0 + colb]      = (_Float16)(acc0[r] * d);
        C[(long long)row * N + col0 + 32 + colb] = (_Float16)(acc1[r] * d);
    }
}

// ---- aggregation: wave per node, fp16 gather, fp32 accumulate --------------
template <int VEC>
__device__ __forceinline__ void vloadh(float* d, const _Float16* p) {
    if constexpr (VEC == 4) {
        half4_t v = *(const half4_t*)p;
        d[0] = (float)v[0]; d[1] = (float)v[1]; d[2] = (float)v[2]; d[3] = (float)v[3];
    } else if constexpr (VEC == 2) {
        half2_t v = *(const half2_t*)p;
        d[0] = (float)v[0]; d[1] = (float)v[1];
    } else {
        d[0] = (float)*p;
    }
}

template <int F, bool OUT_HALF>
__global__ __launch_bounds__(256) void agg_kernel(
        const _Float16* __restrict__ hs, const float* __restrict__ dis,
        const float* __restrict__ bias, const int* __restrict__ off,
        const int* __restrict__ csr, void* __restrict__ outv,
        int N, int do_relu) {
    constexpr int VEC = F / 64;
    int wave = threadIdx.x >> 6;
    int lane = threadIdx.x & 63;
    int n = blockIdx.x * 4 + wave;
    if (n >= N) return;
    int fo = lane * VEC;
    float acc[VEC];
    vloadh<VEC>(acc, hs + (long long)n * F + fo);  // self-loop term
    int s0 = off[n], s1 = off[n + 1];
    int j = s0;
    for (; j + 4 <= s1; j += 4) {
        int i0 = csr[j], i1 = csr[j + 1], i2 = csr[j + 2], i3 = csr[j + 3];
        float v0[VEC], v1[VEC], v2[VEC], v3[VEC];
        vloadh<VEC>(v0, hs + (long long)i0 * F + fo);
        vloadh<VEC>(v1, hs + (long long)i1 * F + fo);
        vloadh<VEC>(v2, hs + (long long)i2 * F + fo);
        vloadh<VEC>(v3, hs + (long long)i3 * F + fo);
        #pragma unroll
        for (int v = 0; v < VEC; ++v)
            acc[v] += (v0[v] + v1[v]) + (v2[v] + v3[v]);
    }
    for (; j < s1; ++j) {
        float v0[VEC];
        vloadh<VEC>(v0, hs + (long long)csr[j] * F + fo);
        #pragma unroll
        for (int v = 0; v < VEC; ++v) acc[v] += v0[v];
    }
    float d = dis[n];
    float o[VEC];
    #pragma unroll
    for (int v = 0; v < VEC; ++v) {
        float val = d * acc[v] + bias[fo + v];
        o[v] = do_relu ? fmaxf(val, 0.f) : val;
    }
    if constexpr (OUT_HALF) {
        _Float16* op = (_Float16*)outv + (long long)n * F + fo;
        if constexpr (VEC == 4) {
            half4_t h; h[0] = (_Float16)o[0]; h[1] = (_Float16)o[1];
            h[2] = (_Float16)o[2]; h[3] = (_Float16)o[3];
            *(half4_t*)op = h;
        } else if constexpr (VEC == 2) {
            half2_t h; h[0] = (_Float16)o[0]; h[1] = (_Float16)o[1];
            *(half2_t*)op = h;
        } else {
            *op = (_Float16)o[0];
        }
    } else {
        float* op = (float*)outv + (long long)n * F + fo;
        #pragma unroll
        for (int v = 0; v < VEC; ++v) op[v] = o[v];
    }
}

// ---------------------------------------------------------------------------
extern "C" void kernel_launch(void* const* d_in, const int* in_sizes, int n_in,
                              void* d_out, int out_size, void* d_ws, size_t ws_size,
                              hipStream_t stream) {
    const float* x  = (const float*)d_in[0];
    const float* W1 = (const float*)d_in[1];
    const float* b1 = (const float*)d_in[2];
    const float* W2 = (const float*)d_in[3];
    const float* b2 = (const float*)d_in[4];
    const float* W3 = (const float*)d_in[5];
    const float* b3 = (const float*)d_in[6];
    const void*  ei = d_in[7];

    const int N = in_sizes[0] / 256;      // 20000
    const int E = in_sizes[7] / 2;        // 320000

    size_t cur = 0;
    auto alloc = [&](size_t bytes) -> void* {
        void* p = (char*)d_ws + cur;
        cur += (bytes + 255) & ~(size_t)255;
        return p;
    };
    int*      flag = (int*)alloc(4);
    int*      deg  = (int*)alloc((size_t)N * 4);
    float*    dis  = (float*)alloc((size_t)N * 4);
    int*      off  = (int*)alloc((size_t)(N + 1) * 4);
    int*      curs = (int*)alloc((size_t)N * 4);
    int*      csr  = (int*)alloc((size_t)E * 4);
    _Float16* xh   = (_Float16*)alloc((size_t)N * 256 * 2);
    _Float16* Wt1  = (_Float16*)alloc(256 * 256 * 2);
    _Float16* Wt2  = (_Float16*)alloc(128 * 256 * 2);
    _Float16* Wt3  = (_Float16*)alloc(64 * 128 * 2);
    _Float16* bufC = (_Float16*)alloc((size_t)N * 256 * 2);  // GEMM out
    _Float16* bufH = (_Float16*)alloc((size_t)N * 256 * 2);  // agg out
    (void)ws_size; (void)n_in; (void)out_size;

    const int T = 256;
    int gN = (N + T - 1) / T;
    int gE = (E + T - 1) / T;
    int gAgg = (N + 3) / 4;

    // --- normalization + CSR build + conversions ---
    detect_i64_kernel<<<1, 64, 0, stream>>>((const int*)ei, in_sizes[7] * 2, flag);
    init_deg_kernel<<<gN, T, 0, stream>>>(deg, N);
    count_deg_kernel<<<gE, T, 0, stream>>>(ei, flag, deg, E);
    dis_kernel<<<gN, T, 0, stream>>>(deg, dis, N);
    scan_kernel<<<1, SCAN_THREADS, 0, stream>>>(deg, off, curs, N, E);
    fill_kernel<<<gE, T, 0, stream>>>(ei, flag, curs, csr, E);
    convert_x_kernel<<<(N * 64 + T - 1) / T, T, 0, stream>>>(x, xh, N * 64);
    prep_weights_kernel<<<(106496 + T - 1) / T, T, 0, stream>>>(W1, W2, W3, Wt1, Wt2, Wt3);

    int gM = (N + 127) / 128;  // 157

    // --- layer 1: xh[N,256] @ W1 -> bufC (fp16); agg -> bufH (fp16) ---
    gemm_mfma_kernel<<<dim3(gM, 4), 256, 0, stream>>>(xh, Wt1, dis, bufC, N, 256, 256);
    agg_kernel<256, true><<<gAgg, 256, 0, stream>>>(bufC, dis, b1, off, csr, bufH, N, 1);
    // --- layer 2: bufH[N,256] @ W2 -> bufC; agg -> bufH ---
    gemm_mfma_kernel<<<dim3(gM, 2), 256, 0, stream>>>(bufH, Wt2, dis, bufC, N, 128, 256);
    agg_kernel<128, true><<<gAgg, 256, 0, stream>>>(bufC, dis, b2, off, csr, bufH, N, 1);
    // --- layer 3: bufH[N,128] @ W3 -> bufC; agg -> d_out (fp32) ---
    gemm_mfma_kernel<<<dim3(gM, 1), 256, 0, stream>>>(bufH, Wt3, dis, bufC, N, 64, 128);
    agg_kernel<64, false><<<gAgg, 256, 0, stream>>>(bufC, dis, b3, off, csr, d_out, N, 0);
}

// Round 4
// 226.231 us; speedup vs baseline: 1.6147x; 1.0441x over previous
//
#include <hip/hip_runtime.h>

// ---------------------------------------------------------------------------
// GCN 3-layer forward on MI355X — fp16 MFMA + deep-unroll gather edition.
//   hs = (h@W) * dis[row]      (MFMA GEMM, fp16 in, fp32 acc, fp16 out)
//   out[n] = relu( dis[n] * (sum_in(n) hs[s] + hs[n]) + b )
// ---------------------------------------------------------------------------

typedef _Float16 half8_t __attribute__((ext_vector_type(8)));
typedef _Float16 half4_t __attribute__((ext_vector_type(4)));
typedef _Float16 half2_t __attribute__((ext_vector_type(2)));
typedef float floatx16 __attribute__((ext_vector_type(16)));

__device__ __forceinline__ int edge_at(const void* p, long long i, int is64) {
    if (is64) return (int)((const long long*)p)[i];
    return ((const int*)p)[i];
}

// ---- fused: detect int64 flag + init deg=1 ---------------------------------
__global__ void setup0_kernel(const int* __restrict__ q, int* __restrict__ flag,
                              int* __restrict__ deg, int N) {
    int i = blockIdx.x * blockDim.x + threadIdx.x;
    if (i < N) deg[i] = 1;  // self-loop
    if (blockIdx.x == 0 && threadIdx.x == 0) {
        int z = 1;
        for (int k = 1; k < 128; k += 2) {
            if (q[k] != 0) { z = 0; break; }
        }
        *flag = z;  // 1 => int64 little-endian
    }
}

__global__ void count_deg_kernel(const void* __restrict__ ei, const int* __restrict__ flag,
                                 int* __restrict__ deg, int E) {
    int e = blockIdx.x * blockDim.x + threadIdx.x;
    if (e < E) {
        int d = edge_at(ei, (long long)E + e, *flag);
        atomicAdd(&deg[d], 1);
    }
}

// ---- fused: exclusive scan of (deg-1) + dis=rsqrt(deg) + cursor ------------
#define SCAN_THREADS 1024
#define SCAN_CHUNK 20
__global__ __launch_bounds__(SCAN_THREADS) void scan_kernel(
        const int* __restrict__ deg, int* __restrict__ off, int* __restrict__ curs,
        float* __restrict__ dis, int N, int E) {
    __shared__ int sums[SCAN_THREADS];
    int t = threadIdx.x;
    int base = t * SCAN_CHUNK;
    int local[SCAN_CHUNK];
    if (base + SCAN_CHUNK <= N) {
        const int4* p = (const int4*)(deg + base);   // deg is 256B-aligned, base%4==0
        #pragma unroll
        for (int i = 0; i < SCAN_CHUNK / 4; ++i) {
            int4 v = p[i];
            local[4 * i] = v.x; local[4 * i + 1] = v.y;
            local[4 * i + 2] = v.z; local[4 * i + 3] = v.w;
        }
    } else {
        for (int i = 0; i < SCAN_CHUNK; ++i) {
            int idx = base + i;
            local[i] = (idx < N) ? deg[idx] : 1;     // pad: deg-1 = 0
        }
    }
    int pre[SCAN_CHUNK];
    int s = 0;
    #pragma unroll
    for (int i = 0; i < SCAN_CHUNK; ++i) { pre[i] = s; s += local[i] - 1; }
    sums[t] = s;
    __syncthreads();
    for (int d = 1; d < SCAN_THREADS; d <<= 1) {
        int v = (t >= d) ? sums[t - d] : 0;
        __syncthreads();
        sums[t] += v;
        __syncthreads();
    }
    int prefix = (t > 0) ? sums[t - 1] : 0;
    for (int i = 0; i < SCAN_CHUNK; ++i) {
        int idx = base + i;
        if (idx < N) {
            int o = prefix + pre[i];
            off[idx] = o; curs[idx] = o;
            dis[idx] = rsqrtf((float)local[i]);
        }
    }
    if (t == 0) off[N] = E;
}

__global__ void fill_kernel(const void* __restrict__ ei, const int* __restrict__ flag,
                            int* __restrict__ cur, int* __restrict__ csr, int E) {
    int e = blockIdx.x * blockDim.x + threadIdx.x;
    if (e < E) {
        int is64 = *flag;
        int s = edge_at(ei, e, is64);
        int d = edge_at(ei, (long long)E + e, is64);
        int slot = atomicAdd(&cur[d], 1);
        csr[slot] = s;
    }
}

// ---- fused: x fp32->fp16 + W[K][N] fp32 -> Wt[N][K] fp16 -------------------
__global__ void convert_kernel(const float* __restrict__ x, _Float16* __restrict__ xh,
                               int total4,
                               const float* __restrict__ W1, const float* __restrict__ W2,
                               const float* __restrict__ W3, _Float16* __restrict__ Wt1,
                               _Float16* __restrict__ Wt2, _Float16* __restrict__ Wt3) {
    int gid = blockIdx.x * blockDim.x + threadIdx.x;
    if (gid < total4) {
        float4 v = *(const float4*)(x + (long long)gid * 4);
        half4_t h;
        h[0] = (_Float16)v.x; h[1] = (_Float16)v.y;
        h[2] = (_Float16)v.z; h[3] = (_Float16)v.w;
        *(half4_t*)(xh + (long long)gid * 4) = h;
        return;
    }
    int id = gid - total4;
    if (id < 65536) {                       // W1: 256x256 -> Wt1[256][256]
        int n = id >> 8, k = id & 255;
        Wt1[n * 256 + k] = (_Float16)W1[k * 256 + n];
    } else if (id < 98304) {                // W2: 256x128 -> Wt2[128][256]
        int i = id - 65536;
        int n = i >> 8, k = i & 255;
        Wt2[n * 256 + k] = (_Float16)W2[k * 128 + n];
    } else if (id < 106496) {               // W3: 128x64 -> Wt3[64][128]
        int i = id - 98304;
        int n = i >> 7, k = i & 127;
        Wt3[n * 128 + k] = (_Float16)W3[k * 64 + n];
    }
}

// ---- MFMA GEMM: C[M,N] = (A[M,K] @ Wt^T) * dis[row], fp16 out --------------
__global__ __launch_bounds__(256) void gemm_mfma_kernel(
        const _Float16* __restrict__ A, const _Float16* __restrict__ Wt,
        const float* __restrict__ dis, _Float16* __restrict__ C,
        int M, int N, int K) {
    constexpr int BM = 128, BN = 64, BK = 32, PAD = 8;
    __shared__ _Float16 As[BM][BK + PAD];
    __shared__ _Float16 Bs[BN][BK + PAD];
    __shared__ float disS[BM];
    const int tid = threadIdx.x;
    const int wave = tid >> 6, lane = tid & 63;
    const int row0 = blockIdx.x * BM, col0 = blockIdx.y * BN;

    if (tid < BM) { int r = row0 + tid; disS[tid] = (r < M) ? dis[r] : 0.f; }

    const int ar0 = tid >> 2, ar1 = ar0 + 64;
    const int ac  = (tid & 3) * 8;
    const int br  = tid >> 2;
    const int bc  = (tid & 3) * 8;
    const long long arow0 = (long long)(row0 + ar0) * K;
    const long long arow1 = (long long)(row0 + ar1) * K;
    const long long brow  = (long long)(col0 + br) * K;
    const bool a0ok = (row0 + ar0) < M, a1ok = (row0 + ar1) < M;
    const float4 f4z = make_float4(0.f, 0.f, 0.f, 0.f);

    float4 pa0 = a0ok ? *(const float4*)(A + arow0 + ac) : f4z;
    float4 pa1 = a1ok ? *(const float4*)(A + arow1 + ac) : f4z;
    float4 pb  = *(const float4*)(Wt + brow + bc);
    *(float4*)&As[ar0][ac] = pa0;
    *(float4*)&As[ar1][ac] = pa1;
    *(float4*)&Bs[br][bc]  = pb;
    __syncthreads();

    floatx16 acc0, acc1;
    #pragma unroll
    for (int i = 0; i < 16; ++i) { acc0[i] = 0.f; acc1[i] = 0.f; }

    const _Float16* ap  = &As[wave * 32 + (lane & 31)][(lane >> 5) * 8];
    const _Float16* bp0 = &Bs[lane & 31][(lane >> 5) * 8];
    const _Float16* bp1 = &Bs[32 + (lane & 31)][(lane >> 5) * 8];

    const int niter = K / BK;
    for (int it = 0; it < niter; ++it) {
        const bool more = (it + 1) < niter;
        if (more) {
            int k0 = (it + 1) * BK;
            pa0 = a0ok ? *(const float4*)(A + arow0 + k0 + ac) : f4z;
            pa1 = a1ok ? *(const float4*)(A + arow1 + k0 + ac) : f4z;
            pb  = *(const float4*)(Wt + brow + k0 + bc);
        }
        half8_t a0  = *(const half8_t*)ap;
        half8_t a1  = *(const half8_t*)(ap + 16);
        half8_t b00 = *(const half8_t*)bp0;
        half8_t b01 = *(const half8_t*)(bp0 + 16);
        half8_t b10 = *(const half8_t*)bp1;
        half8_t b11 = *(const half8_t*)(bp1 + 16);
        acc0 = __builtin_amdgcn_mfma_f32_32x32x16_f16(a0, b00, acc0, 0, 0, 0);
        acc1 = __builtin_amdgcn_mfma_f32_32x32x16_f16(a0, b10, acc1, 0, 0, 0);
        acc0 = __builtin_amdgcn_mfma_f32_32x32x16_f16(a1, b01, acc0, 0, 0, 0);
        acc1 = __builtin_amdgcn_mfma_f32_32x32x16_f16(a1, b11, acc1, 0, 0, 0);
        if (more) {
            __syncthreads();
            *(float4*)&As[ar0][ac] = pa0;
            *(float4*)&As[ar1][ac] = pa1;
            *(float4*)&Bs[br][bc]  = pb;
            __syncthreads();
        }
    }

    const int colb = lane & 31, q = lane >> 5;
    #pragma unroll
    for (int r = 0; r < 16; ++r) {
        int rl = wave * 32 + (r & 3) + 8 * (r >> 2) + 4 * q;
        int row = row0 + rl;
        if (row >= M) continue;
        float d = disS[rl];
        C[(long long)row * N + col0 + colb]      = (_Float16)(acc0[r] * d);
        C[(long long)row * N + col0 + 32 + colb] = (_Float16)(acc1[r] * d);
    }
}

// ---- aggregation: wave per node, 8-deep unrolled fp16 gather ---------------
template <int VEC>
__device__ __forceinline__ void vloadh(float* d, const _Float16* p) {
    if constexpr (VEC == 4) {
        half4_t v = *(const half4_t*)p;
        d[0] = (float)v[0]; d[1] = (float)v[1]; d[2] = (float)v[2]; d[3] = (float)v[3];
    } else if constexpr (VEC == 2) {
        half2_t v = *(const half2_t*)p;
        d[0] = (float)v[0]; d[1] = (float)v[1];
    } else {
        d[0] = (float)*p;
    }
}

template <int F, bool OUT_HALF>
__global__ __launch_bounds__(256) void agg_kernel(
        const _Float16* __restrict__ hs, const float* __restrict__ dis,
        const float* __restrict__ bias, const int* __restrict__ off,
        const int* __restrict__ csr, void* __restrict__ outv,
        int N, int do_relu) {
    constexpr int VEC = F / 64;
    int wave = threadIdx.x >> 6;
    int lane = threadIdx.x & 63;
    int n = blockIdx.x * 4 + wave;
    if (n >= N) return;
    int fo = lane * VEC;
    float acc[VEC];
    vloadh<VEC>(acc, hs + (long long)n * F + fo);  // self-loop term
    int s0 = off[n], s1 = off[n + 1];
    int j = s0;
    // 8 independent gather loads in flight per lane
    for (; j + 8 <= s1; j += 8) {
        int idx[8];
        #pragma unroll
        for (int u = 0; u < 8; ++u) idx[u] = csr[j + u];
        float v[8][VEC];
        #pragma unroll
        for (int u = 0; u < 8; ++u)
            vloadh<VEC>(v[u], hs + (long long)idx[u] * F + fo);
        #pragma unroll
        for (int vv = 0; vv < VEC; ++vv)
            acc[vv] += ((v[0][vv] + v[1][vv]) + (v[2][vv] + v[3][vv]))
                     + ((v[4][vv] + v[5][vv]) + (v[6][vv] + v[7][vv]));
    }
    for (; j + 4 <= s1; j += 4) {
        int i0 = csr[j], i1 = csr[j + 1], i2 = csr[j + 2], i3 = csr[j + 3];
        float v0[VEC], v1[VEC], v2[VEC], v3[VEC];
        vloadh<VEC>(v0, hs + (long long)i0 * F + fo);
        vloadh<VEC>(v1, hs + (long long)i1 * F + fo);
        vloadh<VEC>(v2, hs + (long long)i2 * F + fo);
        vloadh<VEC>(v3, hs + (long long)i3 * F + fo);
        #pragma unroll
        for (int v = 0; v < VEC; ++v)
            acc[v] += (v0[v] + v1[v]) + (v2[v] + v3[v]);
    }
    for (; j < s1; ++j) {
        float v0[VEC];
        vloadh<VEC>(v0, hs + (long long)csr[j] * F + fo);
        #pragma unroll
        for (int v = 0; v < VEC; ++v) acc[v] += v0[v];
    }
    float d = dis[n];
    float o[VEC];
    #pragma unroll
    for (int v = 0; v < VEC; ++v) {
        float val = d * acc[v] + bias[fo + v];
        o[v] = do_relu ? fmaxf(val, 0.f) : val;
    }
    if constexpr (OUT_HALF) {
        _Float16* op = (_Float16*)outv + (long long)n * F + fo;
        if constexpr (VEC == 4) {
            half4_t h; h[0] = (_Float16)o[0]; h[1] = (_Float16)o[1];
            h[2] = (_Float16)o[2]; h[3] = (_Float16)o[3];
            *(half4_t*)op = h;
        } else if constexpr (VEC == 2) {
            half2_t h; h[0] = (_Float16)o[0]; h[1] = (_Float16)o[1];
            *(half2_t*)op = h;
        } else {
            *op = (_Float16)o[0];
        }
    } else {
        float* op = (float*)outv + (long long)n * F + fo;
        #pragma unroll
        for (int v = 0; v < VEC; ++v) op[v] = o[v];
    }
}

// ---------------------------------------------------------------------------
extern "C" void kernel_launch(void* const* d_in, const int* in_sizes, int n_in,
                              void* d_out, int out_size, void* d_ws, size_t ws_size,
                              hipStream_t stream) {
    const float* x  = (const float*)d_in[0];
    const float* W1 = (const float*)d_in[1];
    const float* b1 = (const float*)d_in[2];
    const float* W2 = (const float*)d_in[3];
    const float* b2 = (const float*)d_in[4];
    const float* W3 = (const float*)d_in[5];
    const float* b3 = (const float*)d_in[6];
    const void*  ei = d_in[7];

    const int N = in_sizes[0] / 256;      // 20000
    const int E = in_sizes[7] / 2;        // 320000

    size_t cur = 0;
    auto alloc = [&](size_t bytes) -> void* {
        void* p = (char*)d_ws + cur;
        cur += (bytes + 255) & ~(size_t)255;
        return p;
    };
    int*      flag = (int*)alloc(4);
    int*      deg  = (int*)alloc((size_t)N * 4);
    float*    dis  = (float*)alloc((size_t)N * 4);
    int*      off  = (int*)alloc((size_t)(N + 1) * 4);
    int*      curs = (int*)alloc((size_t)N * 4);
    int*      csr  = (int*)alloc((size_t)E * 4);
    _Float16* xh   = (_Float16*)alloc((size_t)N * 256 * 2);
    _Float16* Wt1  = (_Float16*)alloc(256 * 256 * 2);
    _Float16* Wt2  = (_Float16*)alloc(128 * 256 * 2);
    _Float16* Wt3  = (_Float16*)alloc(64 * 128 * 2);
    _Float16* bufC = (_Float16*)alloc((size_t)N * 256 * 2);
    _Float16* bufH = (_Float16*)alloc((size_t)N * 256 * 2);
    (void)ws_size; (void)n_in; (void)out_size;

    const int T = 256;
    int gN = (N + T - 1) / T;
    int gE = (E + T - 1) / T;
    int gAgg = (N + 3) / 4;
    int convTotal = N * 64 + 106496;

    setup0_kernel<<<gN, T, 0, stream>>>((const int*)ei, flag, deg, N);
    count_deg_kernel<<<gE, T, 0, stream>>>(ei, flag, deg, E);
    scan_kernel<<<1, SCAN_THREADS, 0, stream>>>(deg, off, curs, dis, N, E);
    fill_kernel<<<gE, T, 0, stream>>>(ei, flag, curs, csr, E);
    convert_kernel<<<(convTotal + T - 1) / T, T, 0, stream>>>(
        x, xh, N * 64, W1, W2, W3, Wt1, Wt2, Wt3);

    int gM = (N + 127) / 128;  // 157

    gemm_mfma_kernel<<<dim3(gM, 4), 256, 0, stream>>>(xh, Wt1, dis, bufC, N, 256, 256);
    agg_kernel<256, true><<<gAgg, 256, 0, stream>>>(bufC, dis, b1, off, csr, bufH, N, 1);
    gemm_mfma_kernel<<<dim3(gM, 2), 256, 0, stream>>>(bufH, Wt2, dis, bufC, N, 128, 256);
    agg_kernel<128, true><<<gAgg, 256, 0, stream>>>(bufC, dis, b2, off, csr, bufH, N, 1);
    gemm_mfma_kernel<<<dim3(gM, 1), 256, 0, stream>>>(bufH, Wt3, dis, bufC, N, 64, 128);
    agg_kernel<64, false><<<gAgg, 256, 0, stream>>>(bufC, dis, b3, off, csr, d_out, N, 0);
}